// Round 9
// baseline (238.933 us; speedup 1.0000x reference)
//
#include <hip/hip_runtime.h>
#include <hip/hip_bf16.h>

typedef __hip_bfloat16 bf16;
typedef __bf16 bfx8 __attribute__((ext_vector_type(8)));
typedef float f32x4 __attribute__((ext_vector_type(4)));

#define BM 128

typedef __attribute__((address_space(3))) void lds_void_t;
typedef const __attribute__((address_space(1))) void gbl_void_t;

// ---------------------------------------------------------------------------
// Fused prep: HT[e][n] = bf16(H[n][e]); Hb[n][e] = bf16(H[n][e]);
// de[e] += colsum; dvr[n] += row·w.  H binary -> bf16 exact.
// grid (E/64, N/64), block 256.
__global__ void prep_kernel(const float* __restrict__ H, const float* __restrict__ w,
                            bf16* __restrict__ HT, bf16* __restrict__ Hb,
                            float* __restrict__ de, float* __restrict__ dvr, int N, int E) {
    __shared__ bf16 tile[64][65];
    __shared__ float cred[4][64];
    __shared__ float rred[4][64];
    int eb = blockIdx.x * 64, nb = blockIdx.y * 64;
    int tid = threadIdx.x;
    int c = tid & 63, g = tid >> 6;

    float cs = 0.f;
#pragma unroll
    for (int k = 0; k < 16; k++) {
        int r = g + (k << 2);
        float v = H[(size_t)(nb + r) * E + eb + c];
        bf16 bv = __float2bfloat16(v);
        tile[r][c] = bv;
        Hb[(size_t)(nb + r) * E + eb + c] = bv;   // row-major bf16 copy (coalesced in e)
        cs += v;
    }
    cred[g][c] = cs;
    __syncthreads();
    if (g == 0) {
        float s = cred[0][c] + cred[1][c] + cred[2][c] + cred[3][c];
        atomicAdd(&de[eb + c], s);
    }
    float rs = 0.f;
#pragma unroll
    for (int k = 0; k < 16; k++) {
        int cc = g + (k << 2);
        rs += __bfloat162float(tile[c][cc]) * w[eb + cc];
    }
    rred[g][c] = rs;
    __syncthreads();
    if (g == 1) {
        float s = rred[0][c] + rred[1][c] + rred[2][c] + rred[3][c];
        atomicAdd(&dvr[nb + c], s);
    }
#pragma unroll
    for (int k = 0; k < 16; k++) {
        int r = g + (k << 2);
        HT[(size_t)(eb + r) * N + nb + c] = tile[c][r];  // transposed (coalesced in n)
    }
}

__global__ void finalize_kernel(const float* __restrict__ dvr, const float* __restrict__ de,
                                const float* __restrict__ w, float* __restrict__ dv_is,
                                float* __restrict__ wsc, int N, int E) {
    int i = blockIdx.x * 256 + threadIdx.x;
    if (i < N) dv_is[i] = rsqrtf(dvr[i] + 1e-8f);
    if (i < E) wsc[i] = w[i] / (de[i] + 1e-8f);
}

// x -> xb (bf16): x has 8,388,608 f32 -> 2048 elems/block -> 4096 blocks.
// W -> Wb (bf16): 65,536 f32 -> 32 blocks.  grid 4128.
__global__ void conv_kernel(const float* __restrict__ x, const float* __restrict__ W,
                            bf16* __restrict__ xb, bf16* __restrict__ Wb) {
    int bid = blockIdx.x;
    const float* src = (bid < 4096) ? x : W;
    bf16*        dst = (bid < 4096) ? xb : Wb;
    size_t base = (bid < 4096) ? (size_t)bid : (size_t)(bid - 4096);
    size_t i = (base * 256 + threadIdx.x) * 8;
    f32x4 p0 = *(const f32x4*)&src[i];
    f32x4 p1 = *(const f32x4*)&src[i + 4];
    bfx8 v;
#pragma unroll
    for (int t = 0; t < 4; t++) { v[t] = (__bf16)p0[t]; v[4 + t] = (__bf16)p1[t]; }
    *(bfx8*)&dst[i] = v;
}

// blocks [0,2048): tt[i] = bf16((s0+s1+s2)*wsc[e]); tt may alias s2 (each
//   thread reads s2[i] before writing tt[i]; no restrict on s2/tt).
// blocks [2048,4096): copy Hb (16 MB) -> HbC, 16 elems/thread.
__global__ void combine_copy_kernel(const bf16* __restrict__ s0, const bf16* __restrict__ s1,
                                    const bf16* s2, const float* __restrict__ wsc,
                                    bf16* tt,
                                    const bf16* __restrict__ Hb, bf16* __restrict__ HbC) {
    int bid = blockIdx.x;
    if (bid < 2048) {
        size_t i = ((size_t)bid * 256 + threadIdx.x) * 8;
        size_t e = i & 2047;
        bfx8 a = *(const bfx8*)&s0[i];
        bfx8 b = *(const bfx8*)&s1[i];
        bfx8 c = *(const bfx8*)&s2[i];
        bfx8 v;
#pragma unroll
        for (int t = 0; t < 8; t++)
            v[t] = (__bf16)(((float)a[t] + (float)b[t] + (float)c[t]) * wsc[e + t]);
        *(bfx8*)&tt[i] = v;
    } else {
        size_t j = (((size_t)(bid - 2048)) * 256 + threadIdx.x) * 16;
        bfx8 u0 = *(const bfx8*)&Hb[j];
        bfx8 u1 = *(const bfx8*)&Hb[j + 8];
        *(bfx8*)&HbC[j] = u0;
        *(bfx8*)&HbC[j + 8] = u1;
    }
}

// ---------------------------------------------------------------------------
// Async B^T-form GEMM, 128x64 tile, BK=64 as two stride-32 LDS sub-buffers.
// 4 waves, each 64x32 out (4x2 of 16x16x32). C[row][col] = sum_k A[row][k]*Bt[col][k]
// MODE 0 (K3): z = batch; B += z*1048576; kLen=Kst=256; plain block map;
//              Cb[(z*256+row)*ldc + col] = bf16((acc + rvec[row])*cvec[col])
// MODE 2 (K5): kLen=2048; swizzle 32-wide, RY region;
//              Cf[(col>>8)*1048576 + row*256 + (col&255)] = acc*rvec[row]
// MODE 3 (K4): z = k-slice (3 slices: 1344/1344/1408); swizzle; partial
//              slices: z<2 -> Cv + z*4194304, z==2 -> Cv2; bf16(acc)
template <int MODE, int RY>
__global__ __launch_bounds__(256) void gemm_bt_async(
    const bf16* __restrict__ A, const bf16* __restrict__ Bt, int Kst,
    void* __restrict__ Cv, void* __restrict__ Cv2, int ldc,
    const float* __restrict__ rvec, const float* __restrict__ cvec) {
    __shared__ __align__(16) bf16 SA[2][BM * 32];   // 16 KB
    __shared__ __align__(16) bf16 SB[2][64 * 32];   //  8 KB

    int bx, by;
    if (MODE == 0) {
        bx = blockIdx.x; by = blockIdx.y;
    } else {
        const int lin = blockIdx.y * 32 + blockIdx.x;
        const int xcd = lin & 7, sidx = lin >> 3;
        bx = (xcd & 3) * 8 + (sidx & 7);
        by = (xcd >> 2) * RY + (sidx >> 3);
    }

    int kBase = 0, kLen = Kst;
    if (MODE == 2) kLen = 2048;
    if (MODE == 3) { kBase = blockIdx.z * 1344; kLen = (blockIdx.z == 2) ? 1408 : 1344; }

    const bf16* Bp = (MODE == 0) ? Bt + (size_t)blockIdx.z * 1048576 : Bt;

    const int tid     = threadIdx.x;
    const int rowBase = by * BM;
    const int colBase = bx * 64;
    const int wave = tid >> 6, lane = tid & 63;
    const int wr = (wave >> 1) * 64;
    const int wc = (wave & 1) * 32;
    const int lcol = lane & 15, quad = lane >> 4;

    // staging map: per BK=32 chunk, A = 512 chunks (2/thread), B = 256 (1/thread)
    const int sr = tid >> 2, skc = (tid & 3) << 3;
    const bf16* a0 = &A[(size_t)(rowBase + sr) * Kst + kBase + skc];
    const bf16* a1 = a0 + (size_t)64 * Kst;
    const bf16* b0 = &Bp[(size_t)(colBase + sr) * Kst + kBase + skc];
    bf16* d_a0[2] = {&SA[0][sr * 32 + skc], &SA[1][sr * 32 + skc]};
    bf16* d_a1[2] = {&SA[0][(sr + 64) * 32 + skc], &SA[1][(sr + 64) * 32 + skc]};
    bf16* d_b0[2] = {&SB[0][sr * 32 + skc], &SB[1][sr * 32 + skc]};

    f32x4 acc[4][2];
#pragma unroll
    for (int i = 0; i < 4; i++)
#pragma unroll
        for (int j = 0; j < 2; j++) acc[i][j] = (f32x4){0.f, 0.f, 0.f, 0.f};

    for (int k0 = 0; k0 < kLen; k0 += 64) {
#pragma unroll
        for (int h = 0; h < 2; h++) {
            int kk = k0 + h * 32;
            __builtin_amdgcn_global_load_lds((gbl_void_t*)(a0 + kk), (lds_void_t*)d_a0[h], 16, 0, 0);
            __builtin_amdgcn_global_load_lds((gbl_void_t*)(a1 + kk), (lds_void_t*)d_a1[h], 16, 0, 0);
            __builtin_amdgcn_global_load_lds((gbl_void_t*)(b0 + kk), (lds_void_t*)d_b0[h], 16, 0, 0);
        }
        __syncthreads();

#pragma unroll
        for (int h = 0; h < 2; h++) {
            bfx8 af[4], bfr[2];
#pragma unroll
            for (int i = 0; i < 4; i++)
                af[i] = *(const bfx8*)&SA[h][(wr + i * 16 + lcol) * 32 + quad * 8];
#pragma unroll
            for (int j = 0; j < 2; j++)
                bfr[j] = *(const bfx8*)&SB[h][(wc + j * 16 + lcol) * 32 + quad * 8];
#pragma unroll
            for (int i = 0; i < 4; i++)
#pragma unroll
                for (int j = 0; j < 2; j++)
                    acc[i][j] = __builtin_amdgcn_mfma_f32_16x16x32_bf16(af[i], bfr[j], acc[i][j], 0, 0, 0);
        }
        __syncthreads();
    }

    // C/D layout: col = lane&15, row = quad*4 + reg  [verified m89/m91]
    bf16* Cb = (bf16*)Cv;
    if (MODE == 3 && blockIdx.z == 2) Cb = (bf16*)Cv2;
    if (MODE == 3 && blockIdx.z == 1) Cb = (bf16*)Cv + 4194304;
    float* Cf = (float*)Cv;
    const size_t cRowOff = (MODE == 0) ? (size_t)blockIdx.z * 256 : 0;
#pragma unroll
    for (int i = 0; i < 4; i++) {
#pragma unroll
        for (int j = 0; j < 2; j++) {
#pragma unroll
            for (int r = 0; r < 4; r++) {
                int grow = rowBase + wr + i * 16 + quad * 4 + r;
                int gcol = colBase + wc + j * 16 + lcol;
                float v = acc[i][j][r];
                if (MODE == 0) {
                    v = (v + rvec[grow]) * cvec[gcol];
                    Cb[(cRowOff + grow) * (size_t)ldc + gcol] = __float2bfloat16(v);
                } else if (MODE == 3) {
                    Cb[(size_t)grow * ldc + gcol] = __float2bfloat16(v);
                } else {
                    Cf[(size_t)(gcol >> 8) * 1048576 + (size_t)grow * 256 + (gcol & 255)] =
                        v * rvec[grow];
                }
            }
        }
    }
}

// ---------------------------------------------------------------------------
extern "C" void kernel_launch(void* const* d_in, const int* in_sizes, int n_in,
                              void* d_out, int out_size, void* d_ws, size_t ws_size,
                              hipStream_t stream) {
    const float* x    = (const float*)d_in[0];  // [8,4096,256]
    const float* ew   = (const float*)d_in[1];  // [2048]
    const float* H    = (const float*)d_in[2];  // [4096,2048]
    const float* W    = (const float*)d_in[3];  // [256,256]
    const float* bias = (const float*)d_in[4];  // [256]
    float* out = (float*)d_out;                 // [8,4096,256] f32 = exactly 32 MiB

    const int N = 4096, E = 2048;

    // ws (40.06 MB): small vecs + three big slots
    char* ws = (char*)d_ws;
    float* de    = (float*)(ws);               // 2048 f32
    float* dvr   = (float*)(ws + 8192);        // 4096 f32
    float* dv_is = (float*)(ws + 24576);       // 4096 f32
    float* wsc   = (float*)(ws + 40960);       // 2048 f32
    bf16*  HT    = (bf16*)(ws + 65536);                  // slot1: [E][N] 16 MB (prep->K4)
    bf16*  slot2 = (bf16*)(ws + 65536 + 16777216);       // xs_t (K3->K4), then HbC (combine->K5)
    bf16*  slot3 = (bf16*)(ws + 65536 + 2 * 16777216);   // Wb (conv->K3), s2 (K4), t_t (combine->K5)

    // d_out scratch (dead until K5's final write):
    // [0,16M)  Hb (prep -> combine-copy)
    // [16,32M) xb (conv -> K3), then K4 slices s0/s1
    bf16* Hb = (bf16*)d_out;
    bf16* xb = (bf16*)d_out + 8388608;
    bf16* s01 = xb;

    hipMemsetAsync(ws, 0, 24576, stream);  // de + dvr

    prep_kernel<<<dim3(E / 64, N / 64), 256, 0, stream>>>(H, ew, HT, Hb, de, dvr, N, E);
    finalize_kernel<<<dim3(16), 256, 0, stream>>>(dvr, de, ew, dv_is, wsc, N, E);

    // x -> xb (4096 blocks), W -> Wb (32 blocks, head of slot3)
    conv_kernel<<<dim3(4128), 256, 0, stream>>>(x, W, xb, slot3);

    // K3 (async): xs_t[b*256+o][n] = (sum_d Wb[o][d]*xb[b*4096+n][d] + bias[o]) * dv_is[n]
    // grid (64,2,8) = 1024 blocks (4/CU)
    gemm_bt_async<0, 0><<<dim3(64, 2, 8), 256, 0, stream>>>(
        slot3, xb, 256, slot2, nullptr, 4096, bias, dv_is);

    // K4 (async, split-K=3): slices = partial sums over n-ranges 1344/1344/1408
    // grid (32,16,3) = 1536 blocks (6/CU); s0,s1 -> d_out[16,32M), s2 -> slot3
    gemm_bt_async<3, 8><<<dim3(32, 16, 3), 256, 0, stream>>>(
        slot2, HT, 4096, s01, slot3, 2048, nullptr, nullptr);

    // t_t = bf16((s0+s1+s2)*wsc) into slot3 (in-place over s2), and copy Hb -> slot2
    combine_copy_kernel<<<dim3(4096), 256, 0, stream>>>(
        s01, s01 + 4194304, slot3, wsc, slot3, Hb, slot2);

    // K5 (async): out[b][n][o] = dv_is[n] * sum_e HbC[n][e] * t_t[b*256+o][e]
    // grid (32,32) = 1024 blocks (4/CU)
    gemm_bt_async<2, 16><<<dim3(32, 32), 256, 0, stream>>>(
        slot2, slot3, 2048, out, nullptr, 0, dv_is, nullptr);
}